// Round 1
// 101.697 us; speedup vs baseline: 1.0323x; 1.0323x over previous
//
#include <hip/hip_runtime.h>

#define HD 64      // HIDDEN_DIM
#define VC 128     // VOCAB_SIZE
#define NS 64      // NUM_SLOTS
#define NB 256     // B
#define SL 4096    // L

__device__ __forceinline__ float wsum(float x) {
#pragma unroll
  for (int o = 32; o > 0; o >>= 1) x += __shfl_xor(x, o, 64);
  return x;
}
__device__ __forceinline__ float wmax(float x) {
#pragma unroll
  for (int o = 32; o > 0; o >>= 1) x = fmaxf(x, __shfl_xor(x, o, 64));
  return x;
}

// Kernel 1: per-vocab tables.
// HN[v][h]  = layer_norm(e + FFN(e))           (128 x 64, f32)
// WSM[v][n] = softmax(HN[v] @ gate_w + gate_b) (128 x 64, f32)
__global__ __launch_bounds__(128) void build_tables(
    const float* __restrict__ embed, const float* __restrict__ w1, const float* __restrict__ b1,
    const float* __restrict__ w2, const float* __restrict__ b2,
    const float* __restrict__ ln_g, const float* __restrict__ ln_b,
    const float* __restrict__ gate_w, const float* __restrict__ gate_b,
    float* __restrict__ HN, float* __restrict__ WSM)
{
  const int v = blockIdx.x, t = threadIdx.x;
  __shared__ float s_e[HD], s_f1[2 * HD], s_hn[HD];

  if (t < HD) s_e[t] = embed[v * HD + t];
  __syncthreads();

  // ff1 = relu(e @ w1 + b1), one output per thread (128 outputs)
  float acc = b1[t];
#pragma unroll 8
  for (int h = 0; h < HD; ++h)
    acc = fmaf(s_e[h], w1[h * 2 * HD + t], acc);
  s_f1[t] = fmaxf(acc, 0.f);
  __syncthreads();

  // ff2 + residual + layernorm (wave 0 only: threads 0..63 = one full wave)
  if (t < HD) {
    float a2 = b2[t];
#pragma unroll 8
    for (int j = 0; j < 2 * HD; ++j)
      a2 = fmaf(s_f1[j], w2[j * HD + t], a2);
    float x = s_e[t] + a2;
    float mu = wsum(x) * (1.f / 64.f);
    float d = x - mu;
    float var = wsum(d * d) * (1.f / 64.f);
    float hn = d * rsqrtf(var + 1e-5f) * ln_g[t] + ln_b[t];
    s_hn[t] = hn;
    HN[v * HD + t] = hn;
  }
  __syncthreads();

  // gate softmax over slots (wave 0)
  if (t < NS) {
    float g = gate_b[t];
#pragma unroll 8
    for (int h = 0; h < HD; ++h)
      g = fmaf(s_hn[h], gate_w[h * NS + t], g);
    float m = wmax(g);
    float e = expf(g - m);
    float s = wsum(e);
    WSM[v * NS + t] = e / s;
  }
}

// Kernel 2: one block per batch, 1024 threads (16 waves = 4 waves/SIMD).
// cnt[v] = histogram(seq[b, :L-1]); A = (cnt*WSM)^T @ HN; keys = slot_keys + A;
// sim = l2norm(keys) . l2norm(q); attn = softmax(sim); ctx = attn @ keys;
// out = ctx @ out_w + out_b
// GEMM split 4-way over vocab (quarter qt covers v in [32qt, 32qt+32));
// partials combined through a 32 KB buffer aliased onto the then-dead s_hn.
__global__ __launch_bounds__(1024) void batch_kernel(
    const int* __restrict__ seq, const float* __restrict__ HN, const float* __restrict__ WSM,
    const float* __restrict__ slot_keys, const float* __restrict__ out_w,
    const float* __restrict__ out_b, float* __restrict__ out)
{
  const int b = blockIdx.x, t = threadIdx.x;
  const int lane = t & 63, wave = t >> 6;

  __shared__ int s_cnt[VC];
  __shared__ int s_qtok;
  __align__(16) __shared__ float s_hn[VC * HD];    // 32 KB; post-GEMM reused as kA/kB
  __align__(16) __shared__ float s_wsm[VC * NS];   // 32 KB: cnt-scaled WSM (in place)
  __align__(16) __shared__ float s_keys[NS * HD];  // 16 KB
  __align__(16) __shared__ float s_part[16 * HD];  // 4 KB: ctx partials per wave
  __shared__ float s_q[HD], s_sim[NS], s_attn[NS], s_ctx[HD];

  if (t < VC) s_cnt[t] = 0;
  __syncthreads();

  // Phase 1: histogram (one int4/thread) overlapped with raw HN+WSM staging.
  const int* sb = seq + b * SL;
  const int4 sv = ((const int4*)sb)[t];          // tokens 4t .. 4t+3
  const float4 h0v = ((const float4*)HN)[t];
  const float4 h1v = ((const float4*)HN)[t + 1024];
  const float4 g0v = ((const float4*)WSM)[t];
  const float4 g1v = ((const float4*)WSM)[t + 1024];
  atomicAdd(&s_cnt[sv.x], 1);
  atomicAdd(&s_cnt[sv.y], 1);
  atomicAdd(&s_cnt[sv.z], 1);
  if (t != 1023) atomicAdd(&s_cnt[sv.w], 1);
  else s_qtok = sv.w;                            // seq[b, L-1] excluded from histogram
  ((float4*)s_hn)[t] = h0v;
  ((float4*)s_hn)[t + 1024] = h1v;
  ((float4*)s_wsm)[t] = g0v;
  ((float4*)s_wsm)[t + 1024] = g1v;
  __syncthreads();

  // Phase 2: scale s_wsm rows by cnt (in place, 2 float4/thread); fetch q.
  if (t < HD) s_q[t] = s_hn[s_qtok * HD + t];
  {
    float4 a = ((const float4*)s_wsm)[t];
    float4 c = ((const float4*)s_wsm)[t + 1024];
    const float c0 = (float)s_cnt[t >> 4];            // 16 float4 per 64-float row
    const float c1 = (float)s_cnt[(t + 1024) >> 4];
    a.x *= c0; a.y *= c0; a.z *= c0; a.w *= c0;
    c.x *= c1; c.y *= c1; c.z *= c1; c.w *= c1;
    ((float4*)s_wsm)[t] = a;
    ((float4*)s_wsm)[t + 1024] = c;
  }
  __syncthreads();

  // Phase 3: A += (cnt*WSM)^T @ HN, 4-way vocab split.
  // quarter qt: vocab [32qt, 32qt+32); per-thread 4x4 tile (n0..n0+4, h0..h0+4)
  const int qt = t >> 8;
  const int tid = t & 255;
  const int n0 = (tid >> 4) << 2;
  const int h0 = (tid & 15) << 2;
  const float* hb = s_hn + qt * 32 * HD;
  const float* wb = s_wsm + qt * 32 * NS;

  float accv[4][4];
  if (qt == 0) {
#pragma unroll
    for (int r = 0; r < 4; ++r) {
      const float4 sk = *(const float4*)&slot_keys[(n0 + r) * HD + h0];
      accv[r][0] = sk.x; accv[r][1] = sk.y; accv[r][2] = sk.z; accv[r][3] = sk.w;
    }
  } else {
#pragma unroll
    for (int r = 0; r < 4; ++r)
#pragma unroll
      for (int c = 0; c < 4; ++c) accv[r][c] = 0.f;
  }

#pragma unroll 4
  for (int v = 0; v < 32; ++v) {
    const float4 hv = *(const float4*)&hb[v * HD + h0];  // 16 distinct addrs/wave
    const float4 wv = *(const float4*)&wb[v * NS + n0];  // 4 distinct addrs/wave (broadcast)
    accv[0][0] = fmaf(wv.x, hv.x, accv[0][0]);
    accv[0][1] = fmaf(wv.x, hv.y, accv[0][1]);
    accv[0][2] = fmaf(wv.x, hv.z, accv[0][2]);
    accv[0][3] = fmaf(wv.x, hv.w, accv[0][3]);
    accv[1][0] = fmaf(wv.y, hv.x, accv[1][0]);
    accv[1][1] = fmaf(wv.y, hv.y, accv[1][1]);
    accv[1][2] = fmaf(wv.y, hv.z, accv[1][2]);
    accv[1][3] = fmaf(wv.y, hv.w, accv[1][3]);
    accv[2][0] = fmaf(wv.z, hv.x, accv[2][0]);
    accv[2][1] = fmaf(wv.z, hv.y, accv[2][1]);
    accv[2][2] = fmaf(wv.z, hv.z, accv[2][2]);
    accv[2][3] = fmaf(wv.z, hv.w, accv[2][3]);
    accv[3][0] = fmaf(wv.w, hv.x, accv[3][0]);
    accv[3][1] = fmaf(wv.w, hv.y, accv[3][1]);
    accv[3][2] = fmaf(wv.w, hv.z, accv[3][2]);
    accv[3][3] = fmaf(wv.w, hv.w, accv[3][3]);
  }
  __syncthreads();  // GEMM reads of s_hn/s_wsm complete; both now dead

  // Combine: kA = q0+q1, kB = q2+q3 (aliased onto s_hn), then s_keys = kA+kB.
  float* kA = s_hn;
  float* kB = s_hn + NS * HD;
  if (qt == 1) {
#pragma unroll
    for (int r = 0; r < 4; ++r) {
      float4 st; st.x = accv[r][0]; st.y = accv[r][1]; st.z = accv[r][2]; st.w = accv[r][3];
      *(float4*)&kA[(n0 + r) * HD + h0] = st;
    }
  } else if (qt == 3) {
#pragma unroll
    for (int r = 0; r < 4; ++r) {
      float4 st; st.x = accv[r][0]; st.y = accv[r][1]; st.z = accv[r][2]; st.w = accv[r][3];
      *(float4*)&kB[(n0 + r) * HD + h0] = st;
    }
  }
  __syncthreads();
  if (qt == 0) {
#pragma unroll
    for (int r = 0; r < 4; ++r) {
      float4 p = *(const float4*)&kA[(n0 + r) * HD + h0];
      p.x += accv[r][0]; p.y += accv[r][1]; p.z += accv[r][2]; p.w += accv[r][3];
      *(float4*)&kA[(n0 + r) * HD + h0] = p;
    }
  } else if (qt == 2) {
#pragma unroll
    for (int r = 0; r < 4; ++r) {
      float4 p = *(const float4*)&kB[(n0 + r) * HD + h0];
      p.x += accv[r][0]; p.y += accv[r][1]; p.z += accv[r][2]; p.w += accv[r][3];
      *(float4*)&kB[(n0 + r) * HD + h0] = p;
    }
  }
  __syncthreads();
  {
    float4 a = ((const float4*)kA)[t];   // 4096 floats = 1024 float4, one per thread
    const float4 c = ((const float4*)kB)[t];
    a.x += c.x; a.y += c.y; a.z += c.z; a.w += c.w;
    ((float4*)s_keys)[t] = a;
  }
  __syncthreads();

  // Phase 4: sim[n] — each of 16 waves owns 4 slot rows
  const float qv = s_q[lane];
  const float qn = fmaxf(sqrtf(wsum(qv * qv)), 1e-12f);
#pragma unroll
  for (int r = 0; r < 4; ++r) {
    const int n = (wave << 2) + r;
    const float kv = s_keys[n * HD + lane];
    const float kk = wsum(kv * kv);
    const float kq = wsum(kv * qv);
    if (lane == 0) s_sim[n] = kq / (fmaxf(sqrtf(kk), 1e-12f) * qn);
  }
  __syncthreads();

  // Phase 5: softmax over 64 slots (wave 0)
  if (wave == 0) {
    float svv = s_sim[lane];
    float m = wmax(svv);
    float e = expf(svv - m);
    float ssum = wsum(e);
    s_attn[lane] = e / ssum;
  }
  __syncthreads();

  // Phase 6: ctx partials — wave w covers slots [4w, 4w+4), lane = h
  {
    float c = 0.f;
#pragma unroll
    for (int r = 0; r < 4; ++r) {
      const int n = (wave << 2) + r;
      c = fmaf(s_attn[n], s_keys[n * HD + lane], c);
    }
    s_part[wave * HD + lane] = c;
  }
  __syncthreads();
  if (wave == 0) {
    float c = 0.f;
#pragma unroll
    for (int w = 0; w < 16; ++w) c += s_part[w * HD + lane];
    s_ctx[lane] = c;
  }
  __syncthreads();

  // Phase 7: out = ctx @ out_w + out_b (threads 0..127, coalesced out_w)
  if (t < VC) {
    float o = out_b[t];
#pragma unroll 8
    for (int h = 0; h < HD; ++h)
      o = fmaf(s_ctx[h], out_w[h * VC + t], o);
    out[b * VC + t] = o;
  }
}

extern "C" void kernel_launch(void* const* d_in, const int* in_sizes, int n_in,
                              void* d_out, int out_size, void* d_ws, size_t ws_size,
                              hipStream_t stream) {
  const int* seq         = (const int*)d_in[0];
  const float* embed_w   = (const float*)d_in[1];
  const float* w1        = (const float*)d_in[2];
  const float* b1        = (const float*)d_in[3];
  const float* w2        = (const float*)d_in[4];
  const float* b2        = (const float*)d_in[5];
  const float* ln_g      = (const float*)d_in[6];
  const float* ln_b      = (const float*)d_in[7];
  const float* slot_keys = (const float*)d_in[8];
  // d_in[9] = slot_vals: unused (reference sets vals = keys)
  const float* gate_w    = (const float*)d_in[10];
  const float* gate_b    = (const float*)d_in[11];
  const float* out_w     = (const float*)d_in[12];
  const float* out_b     = (const float*)d_in[13];
  float* out = (float*)d_out;

  float* HN  = (float*)d_ws;       // 128*64 f32
  float* WSM = HN + VC * HD;       // 128*64 f32

  build_tables<<<VC, 128, 0, stream>>>(embed_w, w1, b1, w2, b2, ln_g, ln_b,
                                       gate_w, gate_b, HN, WSM);
  batch_kernel<<<NB, 1024, 0, stream>>>(seq, HN, WSM, slot_keys, out_w, out_b, out);
}